// Round 4
// baseline (25230.782 us; speedup 1.0000x reference)
//
#include <hip/hip_runtime.h>

// Problem constants (fixed shapes from reference)
constexpr int S    = 4096;   // sequence length
constexpr int H    = 512;    // hidden
constexpr int G3   = 1536;   // 3*H
constexpr int NWG  = 32;     // scan worker workgroups (one per XCD0 CU)
constexpr int GRID = 256;    // launched; only blockIdx%8==0 participate
constexpr int FAST_BOUND = 16384;  // one-time L2-poll budget before MALL demotion

// ---------------------------------------------------------------------------
// Fast-path primitives: within one XCD, plain/sc0 stores land in that XCD's
// (writeback) L2 and sc0 loads bypass L1 and probe the same L2.
// ---------------------------------------------------------------------------
__device__ inline uint4 ld4_l2(const void* p) {
    uint4 v;
    asm volatile("global_load_dwordx4 %0, %1, off sc0\n\ts_waitcnt vmcnt(0)"
                 : "=v"(v) : "v"(p) : "memory");
    return v;
}
__device__ inline void st2_l2(void* p, unsigned long long v) {
    asm volatile("global_store_dwordx2 %0, %1, off sc0"
                 :: "v"(p), "v"(v) : "memory");
}

// ---------------------------------------------------------------------------
// Kernel A: gx[t][o] = b_ih[o] + sum_k emb[x[t]][k] * w_ih[o][k]
// (unchanged — passed with absmax 0.0; ~1% of runtime)
// ---------------------------------------------------------------------------
__global__ __launch_bounds__(256) void gemm_gx(
    const int* __restrict__ x, const float* __restrict__ emb,
    const float* __restrict__ w_ih, const float* __restrict__ b_ih,
    float* __restrict__ gx)
{
    __shared__ alignas(16) float As[128][36];
    __shared__ alignas(16) float Bs[32][132];

    const int tid  = threadIdx.x;
    const int row0 = (blockIdx.x / 12) * 128;
    const int col0 = (blockIdx.x % 12) * 128;
    const int tx   = tid & 15;
    const int ty   = tid >> 4;

    float acc[8][8] = {};

    for (int k0 = 0; k0 < H; k0 += 32) {
        #pragma unroll
        for (int p = 0; p < 4; ++p) {
            const int rl = (tid >> 3) + 32 * p;
            const int kk = (tid & 7) * 4;
            const int xi = x[row0 + rl];
            const float4 va = *reinterpret_cast<const float4*>(
                emb + (size_t)xi * H + k0 + kk);
            *reinterpret_cast<float4*>(&As[rl][kk]) = va;

            const float4 vb = *reinterpret_cast<const float4*>(
                w_ih + (size_t)(col0 + rl) * H + k0 + kk);
            Bs[kk + 0][rl] = vb.x; Bs[kk + 1][rl] = vb.y;
            Bs[kk + 2][rl] = vb.z; Bs[kk + 3][rl] = vb.w;
        }
        __syncthreads();

        #pragma unroll
        for (int kk = 0; kk < 32; ++kk) {
            float a[8], b[8];
            #pragma unroll
            for (int q = 0; q < 4; ++q) {
                a[q]     = As[ty * 4 + q][kk];
                a[4 + q] = As[ty * 4 + 64 + q][kk];
            }
            const float4 b0 = *reinterpret_cast<const float4*>(&Bs[kk][tx * 4]);
            const float4 b1 = *reinterpret_cast<const float4*>(&Bs[kk][tx * 4 + 64]);
            b[0]=b0.x; b[1]=b0.y; b[2]=b0.z; b[3]=b0.w;
            b[4]=b1.x; b[5]=b1.y; b[6]=b1.z; b[7]=b1.w;
            #pragma unroll
            for (int ri = 0; ri < 8; ++ri)
                #pragma unroll
                for (int ci = 0; ci < 8; ++ci)
                    acc[ri][ci] = fmaf(a[ri], b[ci], acc[ri][ci]);
        }
        __syncthreads();
    }

    float bi[8];
    #pragma unroll
    for (int q = 0; q < 4; ++q) {
        bi[q]     = b_ih[col0 + tx * 4 + q];
        bi[4 + q] = b_ih[col0 + tx * 4 + 64 + q];
    }
    #pragma unroll
    for (int ri = 0; ri < 8; ++ri) {
        const int rr = row0 + ty * 4 + (ri & 3) + ((ri >> 2) << 6);
        float4 o0, o1;
        o0.x = acc[ri][0] + bi[0]; o0.y = acc[ri][1] + bi[1];
        o0.z = acc[ri][2] + bi[2]; o0.w = acc[ri][3] + bi[3];
        o1.x = acc[ri][4] + bi[4]; o1.y = acc[ri][5] + bi[5];
        o1.z = acc[ri][6] + bi[6]; o1.w = acc[ri][7] + bi[7];
        *reinterpret_cast<float4*>(gx + (size_t)rr * G3 + col0 + tx * 4)      = o0;
        *reinterpret_cast<float4*>(gx + (size_t)rr * G3 + col0 + tx * 4 + 64) = o1;
    }
}

// ---------------------------------------------------------------------------
// Kernel B: persistent GRU scan, same-XCD fast path + proven MALL fallback.
//   - 256 blocks launched; participants are blockIdx%8==0 (round-robin
//     block->XCD mapping => all 32 winners share one XCD). slice = bid/8.
//   - Producers dual-store each (tag<<32|value): plain sc0 store into hl2
//     (stays in the shared XCD L2) AND relaxed agent atomic into hml
//     (round-1/3-proven MALL path).
//   - Consumers poll hl2 (sc0 dwordx4); after a one-time FAST_BOUND miss
//     budget they demote permanently to the hml atomic poll. Data is NEVER
//     consumed without a matching tag => placement failure costs speed only.
//   - Weights loaded via volatile scalar loads: non-rematerializable, so the
//     allocator must keep all 96 floats/thread in VGPRs (round 3: VGPR=68
//     proved the compiler was re-loading them from L2 every step).
//   - One barrier per step: a successful tag-(s+1) poll is causally after
//     every lane's step-s LDS reads (reads -> butterfly -> lane0 store).
// ---------------------------------------------------------------------------
__global__ __launch_bounds__(256, 1) void gru_scan(
    const float* __restrict__ gx,
    const float* __restrict__ w_hh,
    const float* __restrict__ b_hh,
    const float* __restrict__ dec_w,
    const float* __restrict__ dec_b,
    const float* __restrict__ target,
    unsigned long long* __restrict__ hl2,   // [2][H] fast (XCD-L2) tag|value
    unsigned long long* __restrict__ hml,   // [2][H] slow (MALL)   tag|value
    float* __restrict__ out)
{
    const int bid = blockIdx.x;
    if ((bid & 7) != 0) return;            // one XCD's blocks only
    const int k = bid >> 3;                // slice 0..31

    __shared__ float h_lds[H];

    const int tid = threadIdx.x;
    const int l   = tid & 15;    // lane within 16-lane group (column owner)
    const int g   = tid >> 4;    // group id 0..15
    const int i   = k * 16 + g;  // owned hidden index
    const int e0  = 2 * tid, e1 = 2 * tid + 1;   // owned h slots (both paths)

    // Register-resident recurrent weights via volatile loads (no remat).
    float4 wr[8], wz[8], wn[8];
    #pragma unroll
    for (int j = 0; j < 8; ++j) {
        const volatile float* pr =
            (const volatile float*)(w_hh + (size_t)i * H + 4 * l + 64 * j);
        const volatile float* pz = pr + (size_t)H * H;
        const volatile float* pn = pz + (size_t)H * H;
        wr[j] = make_float4(pr[0], pr[1], pr[2], pr[3]);
        wz[j] = make_float4(pz[0], pz[1], pz[2], pz[3]);
        wn[j] = make_float4(pn[0], pn[1], pn[2], pn[3]);
    }
    const float bhr = b_hh[i], bhz = b_hh[H + i], bhn = b_hh[2 * H + i];

    float gxr = 0.f, gxz = 0.f, gxn = 0.f;
    if (l == 0) { gxr = gx[i]; gxz = gx[H + i]; gxn = gx[2 * H + i]; }

    bool use_mall = false;

    for (int s = 0; s < S; ++s) {
        // --- obtain h_s into LDS ---
        if (s == 0) {
            h_lds[e0] = 0.f; h_lds[e1] = 0.f;
        } else {
            const unsigned tg   = (unsigned)s;
            const size_t   boff = (size_t)(s & 1) * H;
            unsigned x0, x1;
            bool got = false;
            if (!use_mall) {
                const uint4* src =
                    reinterpret_cast<const uint4*>(hl2 + boff) + tid;
                uint4 v = ld4_l2(src);
                int it = 0;
                while (!(v.y == tg && v.w == tg) && it < FAST_BOUND) {
                    ++it; v = ld4_l2(src);
                }
                if (v.y == tg && v.w == tg) { x0 = v.x; x1 = v.z; got = true; }
                else use_mall = true;       // sticky demotion, proven path
            }
            if (!got) {
                unsigned long long* src = hml + boff;
                unsigned long long v0 = 0, v1 = 0;
                bool d0 = false, d1 = false;
                while (!(d0 && d1)) {
                    if (!d0) { v0 = __hip_atomic_load(src + e0, __ATOMIC_RELAXED,
                                                      __HIP_MEMORY_SCOPE_AGENT);
                               d0 = (unsigned)(v0 >> 32) == tg; }
                    if (!d1) { v1 = __hip_atomic_load(src + e1, __ATOMIC_RELAXED,
                                                      __HIP_MEMORY_SCOPE_AGENT);
                               d1 = (unsigned)(v1 >> 32) == tg; }
                }
                x0 = (unsigned)v0; x1 = (unsigned)v1;
            }
            h_lds[e0] = __uint_as_float(x0);
            h_lds[e1] = __uint_as_float(x1);
        }
        __syncthreads();

        const float hp = h_lds[i];

        // --- three 512-dots: lane l covers cols 4l+64j+q via ds_read_b128 ---
        float ar = 0.f, az = 0.f, an = 0.f;
        #pragma unroll
        for (int j = 0; j < 8; ++j) {
            const float4 hv =
                *reinterpret_cast<const float4*>(&h_lds[64 * j + 4 * l]);
            ar = fmaf(wr[j].x, hv.x, fmaf(wr[j].y, hv.y,
                 fmaf(wr[j].z, hv.z, fmaf(wr[j].w, hv.w, ar))));
            az = fmaf(wz[j].x, hv.x, fmaf(wz[j].y, hv.y,
                 fmaf(wz[j].z, hv.z, fmaf(wz[j].w, hv.w, az))));
            an = fmaf(wn[j].x, hv.x, fmaf(wn[j].y, hv.y,
                 fmaf(wn[j].z, hv.z, fmaf(wn[j].w, hv.w, an))));
        }
        #pragma unroll
        for (int m = 8; m >= 1; m >>= 1) {   // butterfly within 16-lane group
            ar += __shfl_xor(ar, m);
            az += __shfl_xor(az, m);
            an += __shfl_xor(an, m);
        }

        if (l == 0) {
            const float r  = 1.f / (1.f + __expf(-(gxr + ar + bhr)));
            const float z  = 1.f / (1.f + __expf(-(gxz + az + bhz)));
            const float nn = tanhf(gxn + r * (an + bhn));
            const float hnew = (1.f - z) * nn + z * hp;
            const unsigned long long pv =
                ((unsigned long long)(unsigned)(s + 1) << 32) |
                (unsigned long long)__float_as_uint(hnew);
            const size_t dsts = (size_t)((s + 1) & 1) * H + i;
            st2_l2(hl2 + dsts, pv);                      // fast path (XCD L2)
            __hip_atomic_store(hml + dsts, pv,           // proven path (MALL)
                               __ATOMIC_RELAXED, __HIP_MEMORY_SCOPE_AGENT);
            // prefetch next step's gx slice (hidden under next poll/compute)
            const int sn = (s + 1 < S) ? (s + 1) : s;
            gxr = gx[(size_t)sn * G3 + i];
            gxz = gx[(size_t)sn * G3 + H + i];
            gxn = gx[(size_t)sn * G3 + 2 * H + i];
        }
        // no second barrier: next poll success is causally after all reads.
    }

    // --- epilogue: slice-0 WG gathers h_S (tag S, buffer 0), computes BCE ---
    if (k == 0) {
        const unsigned tg = (unsigned)S;
        unsigned x0, x1;
        bool got = false;
        if (!use_mall) {
            const uint4* src = reinterpret_cast<const uint4*>(hl2) + tid;
            uint4 v = ld4_l2(src);
            int it = 0;
            while (!(v.y == tg && v.w == tg) && it < FAST_BOUND) {
                ++it; v = ld4_l2(src);
            }
            if (v.y == tg && v.w == tg) { x0 = v.x; x1 = v.z; got = true; }
            else use_mall = true;
        }
        if (!got) {
            unsigned long long v0 = 0, v1 = 0;
            bool d0 = false, d1 = false;
            while (!(d0 && d1)) {
                if (!d0) { v0 = __hip_atomic_load(hml + e0, __ATOMIC_RELAXED,
                                                  __HIP_MEMORY_SCOPE_AGENT);
                           d0 = (unsigned)(v0 >> 32) == tg; }
                if (!d1) { v1 = __hip_atomic_load(hml + e1, __ATOMIC_RELAXED,
                                                  __HIP_MEMORY_SCOPE_AGENT);
                           d1 = (unsigned)(v1 >> 32) == tg; }
            }
            x0 = (unsigned)v0; x1 = (unsigned)v1;
        }
        h_lds[e0] = __uint_as_float(x0);
        h_lds[e1] = __uint_as_float(x1);
        __syncthreads();

        if (tid < 64) {
            float p = 0.f;
            #pragma unroll
            for (int j = 0; j < 8; ++j)
                p = fmaf(h_lds[tid + 64 * j], dec_w[tid + 64 * j], p);
            #pragma unroll
            for (int m = 32; m >= 1; m >>= 1) p += __shfl_xor(p, m);
            if (tid == 0) {
                const float xl = p + dec_b[0];
                const float t  = target[0];
                const float loss = fmaxf(xl, 0.f) - xl * t +
                                   log1pf(__expf(-fabsf(xl)));
                out[0] = loss;
            }
        }
    }
}

// ---------------------------------------------------------------------------
extern "C" void kernel_launch(void* const* d_in, const int* in_sizes, int n_in,
                              void* d_out, int out_size, void* d_ws, size_t ws_size,
                              hipStream_t stream) {
    const int*   x      = (const int*)d_in[0];
    const float* target = (const float*)d_in[1];
    const float* emb    = (const float*)d_in[2];
    const float* w_ih   = (const float*)d_in[3];
    const float* w_hh   = (const float*)d_in[4];
    const float* b_ih   = (const float*)d_in[5];
    const float* b_hh   = (const float*)d_in[6];
    const float* dec_w  = (const float*)d_in[7];
    const float* dec_b  = (const float*)d_in[8];
    float*       out    = (float*)d_out;

    float* gx = (float*)d_ws;                                   // [S][1536] = 25.2 MB
    unsigned long long* hl2 =
        (unsigned long long*)((char*)d_ws + (size_t)S * G3 * sizeof(float));
    unsigned long long* hml = hl2 + 2 * H;

    // Clear both tag buffers every launch (graph replays start from a kernel
    // boundary, so the dispatch-level cache invalidate makes zeros visible).
    hipMemsetAsync(hl2, 0, 4 * H * sizeof(unsigned long long), stream);

    gemm_gx<<<dim3(32 * 12), dim3(256), 0, stream>>>(x, emb, w_ih, b_ih, gx);
    gru_scan<<<dim3(GRID), dim3(256), 0, stream>>>(gx, w_hh, b_hh, dec_w, dec_b,
                                                   target, hl2, hml, out);
}

// Round 5
// 9392.381 us; speedup vs baseline: 2.6863x; 2.6863x over previous
//
#include <hip/hip_runtime.h>

// Problem constants (fixed shapes from reference)
constexpr int S   = 4096;   // sequence length
constexpr int H   = 512;    // hidden
constexpr int G3  = 1536;   // 3*H
constexpr int NWG = 32;     // scan worker workgroups; each owns H/NWG = 16 hidden idx
constexpr int FAST_TRIES = 256;  // per-step x4-poll budget before sticky atomic demotion

// Poll two adjacent (tag|value) u64s with one dwordx4 straight from the
// coherence point (sc0 = L1 bypass, sc1 = L2 bypass -> MALL). Same visibility
// domain as the proven agent-scope atomics; 8B halves are tear-free.
__device__ inline uint4 ld4_mall(const void* p) {
    uint4 v;
    asm volatile("global_load_dwordx4 %0, %1, off sc0 sc1\n\ts_waitcnt vmcnt(0)"
                 : "=v"(v) : "v"(p) : "memory");
    return v;
}

// ---------------------------------------------------------------------------
// Kernel A: gx[t][o] = b_ih[o] + sum_k emb[x[t]][k] * w_ih[o][k]
// (unchanged — passed with absmax 0.0; ~1% of runtime)
// ---------------------------------------------------------------------------
__global__ __launch_bounds__(256) void gemm_gx(
    const int* __restrict__ x, const float* __restrict__ emb,
    const float* __restrict__ w_ih, const float* __restrict__ b_ih,
    float* __restrict__ gx)
{
    __shared__ alignas(16) float As[128][36];
    __shared__ alignas(16) float Bs[32][132];

    const int tid  = threadIdx.x;
    const int row0 = (blockIdx.x / 12) * 128;
    const int col0 = (blockIdx.x % 12) * 128;
    const int tx   = tid & 15;
    const int ty   = tid >> 4;

    float acc[8][8] = {};

    for (int k0 = 0; k0 < H; k0 += 32) {
        #pragma unroll
        for (int p = 0; p < 4; ++p) {
            const int rl = (tid >> 3) + 32 * p;
            const int kk = (tid & 7) * 4;
            const int xi = x[row0 + rl];
            const float4 va = *reinterpret_cast<const float4*>(
                emb + (size_t)xi * H + k0 + kk);
            *reinterpret_cast<float4*>(&As[rl][kk]) = va;

            const float4 vb = *reinterpret_cast<const float4*>(
                w_ih + (size_t)(col0 + rl) * H + k0 + kk);
            Bs[kk + 0][rl] = vb.x; Bs[kk + 1][rl] = vb.y;
            Bs[kk + 2][rl] = vb.z; Bs[kk + 3][rl] = vb.w;
        }
        __syncthreads();

        #pragma unroll
        for (int kk = 0; kk < 32; ++kk) {
            float a[8], b[8];
            #pragma unroll
            for (int q = 0; q < 4; ++q) {
                a[q]     = As[ty * 4 + q][kk];
                a[4 + q] = As[ty * 4 + 64 + q][kk];
            }
            const float4 b0 = *reinterpret_cast<const float4*>(&Bs[kk][tx * 4]);
            const float4 b1 = *reinterpret_cast<const float4*>(&Bs[kk][tx * 4 + 64]);
            b[0]=b0.x; b[1]=b0.y; b[2]=b0.z; b[3]=b0.w;
            b[4]=b1.x; b[5]=b1.y; b[6]=b1.z; b[7]=b1.w;
            #pragma unroll
            for (int ri = 0; ri < 8; ++ri)
                #pragma unroll
                for (int ci = 0; ci < 8; ++ci)
                    acc[ri][ci] = fmaf(a[ri], b[ci], acc[ri][ci]);
        }
        __syncthreads();
    }

    float bi[8];
    #pragma unroll
    for (int q = 0; q < 4; ++q) {
        bi[q]     = b_ih[col0 + tx * 4 + q];
        bi[4 + q] = b_ih[col0 + tx * 4 + 64 + q];
    }
    #pragma unroll
    for (int ri = 0; ri < 8; ++ri) {
        const int rr = row0 + ty * 4 + (ri & 3) + ((ri >> 2) << 6);
        float4 o0, o1;
        o0.x = acc[ri][0] + bi[0]; o0.y = acc[ri][1] + bi[1];
        o0.z = acc[ri][2] + bi[2]; o0.w = acc[ri][3] + bi[3];
        o1.x = acc[ri][4] + bi[4]; o1.y = acc[ri][5] + bi[5];
        o1.z = acc[ri][6] + bi[6]; o1.w = acc[ri][7] + bi[7];
        *reinterpret_cast<float4*>(gx + (size_t)rr * G3 + col0 + tx * 4)      = o0;
        *reinterpret_cast<float4*>(gx + (size_t)rr * G3 + col0 + tx * 4 + 64) = o1;
    }
}

// ---------------------------------------------------------------------------
// Kernel B: persistent GRU scan. 32 WGs x 256 threads.
// Sync protocol = round 1/3 PROVEN: tag-in-data u64 (tag<<32|f32), double
// buffer, relaxed agent-scope atomic stores, unbounded tag-gated consume,
// two barriers per step. Changes this round:
//   - W_hh slice staged in LDS (96 KB; gfx950 allows >64KB static LDS):
//     rounds 3/4 proved the compiler will NOT keep 96 floats/thread in VGPRs
//     (remat from L2 / scratch spill, VGPR=68) — LDS makes the weight path
//     deterministic: 24x ds_read_b128/thread/step, 16-lane-contiguous
//     (conflict-free), overlapped with the FMA chain.
//   - Poll via one dwordx4 sc0 sc1 (MALL-direct) instead of two u64 atomic
//     loads; after FAST_TRIES misses in a step, sticky-demote to the proven
//     atomic-pair poll. Data is never consumed without a matching tag.
// NOTE kept barrier 2: poll success only proves a thread's OWN two slots are
// ready, not that sibling waves of its WG finished reading h_lds — dropping
// the end barrier (round 4) is a genuine WG-internal race.
// ---------------------------------------------------------------------------
__global__ __launch_bounds__(256) void gru_scan(
    const float* __restrict__ gx,
    const float* __restrict__ w_hh,
    const float* __restrict__ b_hh,
    const float* __restrict__ dec_w,
    const float* __restrict__ dec_b,
    const float* __restrict__ target,
    unsigned long long* __restrict__ hbuf,   // [2][H] (tag|value)
    float* __restrict__ out)
{
    __shared__ alignas(16) float w_lds[3 * 16 * 512];  // 96 KB: [gate][row][512]
    __shared__ alignas(16) float h_lds[H];             // 2 KB

    const int k   = blockIdx.x;
    const int tid = threadIdx.x;
    const int l   = tid & 15;    // lane within 16-lane group (column owner)
    const int g   = tid >> 4;    // group id 0..15
    const int i   = k * 16 + g;  // owned hidden index

    // --- stage W_hh slice into LDS: rows (q*H + 16k + r), 6144 float4s ---
    #pragma unroll
    for (int m = 0; m < 24; ++m) {
        const int p = tid + 256 * m;      // float4 index 0..6143
        const int q = p >> 11;            // gate 0..2   (2048 f4 per gate)
        const int r = (p >> 7) & 15;      // row within gate
        const int c = p & 127;            // float4 column
        const float4 v = *reinterpret_cast<const float4*>(
            w_hh + ((size_t)q * H + k * 16 + r) * H + 4 * c);
        *reinterpret_cast<float4*>(&w_lds[((q * 16 + r) << 9) + 4 * c]) = v;
    }

    const float bhr = b_hh[i], bhz = b_hh[H + i], bhn = b_hh[2 * H + i];

    float gxr = 0.f, gxz = 0.f, gxn = 0.f;
    if (l == 0) { gxr = gx[i]; gxz = gx[H + i]; gxn = gx[2 * H + i]; }
    __syncthreads();   // w_lds ready

    // per-thread LDS base pointers (row = q*16+g, col base 4l)
    const float* wr_ = &w_lds[((0 * 16 + g) << 9) + 4 * l];
    const float* wz_ = &w_lds[((1 * 16 + g) << 9) + 4 * l];
    const float* wn_ = &w_lds[((2 * 16 + g) << 9) + 4 * l];

    bool slow = false;   // sticky demotion to proven atomic poll

    for (int s = 0; s < S; ++s) {
        // --- obtain h_s into LDS (thread owns slots 2tid, 2tid+1) ---
        if (s == 0) {
            h_lds[2 * tid] = 0.f; h_lds[2 * tid + 1] = 0.f;
        } else {
            const unsigned tg   = (unsigned)s;
            const size_t   boff = (size_t)(s & 1) * H;
            unsigned x0, x1;
            bool got = false;
            if (!slow) {
                const void* src = (const char*)(hbuf + boff) + 16 * (size_t)tid;
                uint4 v = ld4_mall(src);
                int it = 0;
                while (!(v.y == tg && v.w == tg) && it < FAST_TRIES) {
                    ++it; v = ld4_mall(src);
                }
                if (v.y == tg && v.w == tg) { x0 = v.x; x1 = v.z; got = true; }
                else slow = true;
            }
            if (!got) {   // proven path (rounds 1/3)
                unsigned long long* src = hbuf + boff;
                unsigned long long v0 = 0, v1 = 0;
                bool d0 = false, d1 = false;
                while (!(d0 && d1)) {
                    if (!d0) { v0 = __hip_atomic_load(src + 2 * tid,
                                   __ATOMIC_RELAXED, __HIP_MEMORY_SCOPE_AGENT);
                               d0 = (unsigned)(v0 >> 32) == tg; }
                    if (!d1) { v1 = __hip_atomic_load(src + 2 * tid + 1,
                                   __ATOMIC_RELAXED, __HIP_MEMORY_SCOPE_AGENT);
                               d1 = (unsigned)(v1 >> 32) == tg; }
                }
                x0 = (unsigned)v0; x1 = (unsigned)v1;
            }
            h_lds[2 * tid]     = __uint_as_float(x0);
            h_lds[2 * tid + 1] = __uint_as_float(x1);
        }
        __syncthreads();

        const float hp = h_lds[i];

        // --- three 512-dots: lane l covers cols 4l+64j; weights from LDS ---
        float ar = 0.f, az = 0.f, an = 0.f;
        #pragma unroll
        for (int j = 0; j < 8; ++j) {
            const float4 hv = *reinterpret_cast<const float4*>(&h_lds[64 * j + 4 * l]);
            const float4 a  = *reinterpret_cast<const float4*>(wr_ + 64 * j);
            const float4 b  = *reinterpret_cast<const float4*>(wz_ + 64 * j);
            const float4 c  = *reinterpret_cast<const float4*>(wn_ + 64 * j);
            ar = fmaf(a.x, hv.x, fmaf(a.y, hv.y, fmaf(a.z, hv.z, fmaf(a.w, hv.w, ar))));
            az = fmaf(b.x, hv.x, fmaf(b.y, hv.y, fmaf(b.z, hv.z, fmaf(b.w, hv.w, az))));
            an = fmaf(c.x, hv.x, fmaf(c.y, hv.y, fmaf(c.z, hv.z, fmaf(c.w, hv.w, an))));
        }
        #pragma unroll
        for (int m = 8; m >= 1; m >>= 1) {   // butterfly within 16-lane group
            ar += __shfl_xor(ar, m);
            az += __shfl_xor(az, m);
            an += __shfl_xor(an, m);
        }

        if (l == 0) {
            const float r  = 1.f / (1.f + __expf(-(gxr + ar + bhr)));
            const float z  = 1.f / (1.f + __expf(-(gxz + az + bhz)));
            const float nn = tanhf(gxn + r * (an + bhn));
            const float hnew = (1.f - z) * nn + z * hp;
            const unsigned long long pv =
                ((unsigned long long)(unsigned)(s + 1) << 32) |
                (unsigned long long)__float_as_uint(hnew);
            __hip_atomic_store(hbuf + (size_t)((s + 1) & 1) * H + i, pv,
                               __ATOMIC_RELAXED, __HIP_MEMORY_SCOPE_AGENT);
            // prefetch next step's gx slice (completes under next poll)
            const int sn = (s + 1 < S) ? (s + 1) : s;
            gxr = gx[(size_t)sn * G3 + i];
            gxz = gx[(size_t)sn * G3 + H + i];
            gxn = gx[(size_t)sn * G3 + 2 * H + i];
        }
        __syncthreads();   // protect h_lds: poll success != WG-wide read-done
    }

    // --- epilogue: WG0 gathers h_S (tag S, buffer 0), computes BCE ---
    if (k == 0) {
        unsigned long long v0 = 0, v1 = 0;
        bool d0 = false, d1 = false;
        while (!(d0 && d1)) {
            if (!d0) { v0 = __hip_atomic_load(hbuf + 2 * tid,
                           __ATOMIC_RELAXED, __HIP_MEMORY_SCOPE_AGENT);
                       d0 = (unsigned)(v0 >> 32) == (unsigned)S; }
            if (!d1) { v1 = __hip_atomic_load(hbuf + 2 * tid + 1,
                           __ATOMIC_RELAXED, __HIP_MEMORY_SCOPE_AGENT);
                       d1 = (unsigned)(v1 >> 32) == (unsigned)S; }
        }
        h_lds[2 * tid]     = __uint_as_float((unsigned)v0);
        h_lds[2 * tid + 1] = __uint_as_float((unsigned)v1);
        __syncthreads();

        if (tid < 64) {
            float p = 0.f;
            #pragma unroll
            for (int j = 0; j < 8; ++j)
                p = fmaf(h_lds[tid + 64 * j], dec_w[tid + 64 * j], p);
            #pragma unroll
            for (int m = 32; m >= 1; m >>= 1) p += __shfl_xor(p, m);
            if (tid == 0) {
                const float xl = p + dec_b[0];
                const float t  = target[0];
                const float loss = fmaxf(xl, 0.f) - xl * t +
                                   log1pf(__expf(-fabsf(xl)));
                out[0] = loss;
            }
        }
    }
}

// ---------------------------------------------------------------------------
extern "C" void kernel_launch(void* const* d_in, const int* in_sizes, int n_in,
                              void* d_out, int out_size, void* d_ws, size_t ws_size,
                              hipStream_t stream) {
    const int*   x      = (const int*)d_in[0];
    const float* target = (const float*)d_in[1];
    const float* emb    = (const float*)d_in[2];
    const float* w_ih   = (const float*)d_in[3];
    const float* w_hh   = (const float*)d_in[4];
    const float* b_ih   = (const float*)d_in[5];
    const float* b_hh   = (const float*)d_in[6];
    const float* dec_w  = (const float*)d_in[7];
    const float* dec_b  = (const float*)d_in[8];
    float*       out    = (float*)d_out;

    float* gx = (float*)d_ws;                                   // [S][1536] = 25.2 MB
    unsigned long long* hbuf =
        (unsigned long long*)((char*)d_ws + (size_t)S * G3 * sizeof(float)); // [2][H]

    // Clear tags every launch so graph replays can't match stale tags.
    hipMemsetAsync(hbuf, 0, 2 * H * sizeof(unsigned long long), stream);

    gemm_gx<<<dim3(32 * 12), dim3(256), 0, stream>>>(x, emb, w_ih, b_ih, gx);
    gru_scan<<<dim3(NWG), dim3(256), 0, stream>>>(gx, w_hh, b_hh, dec_w, dec_b,
                                                  target, hbuf, out);
}